// Round 17
// baseline (185.997 us; speedup 1.0000x reference)
//
#include <hip/hip_runtime.h>
#include <hip/hip_bf16.h>

typedef unsigned short u16;
typedef unsigned int u32;
typedef __attribute__((ext_vector_type(8))) short short8;   // 8 bf16 (4 VGPRs)
typedef __attribute__((ext_vector_type(4))) float f32x4;    // MFMA accumulator
typedef __attribute__((ext_vector_type(4))) u16 u16x4;

static constexpr int Bb = 512, Tt = 256, Cc = 768, Hh = 64;

__device__ __forceinline__ u16 f2bf(float f) {
    __hip_bfloat16 h = __float2bfloat16(f);   // RNE
    union { __hip_bfloat16 h; u16 u; } v; v.h = h;
    return v.u;
}

__device__ __forceinline__ void gll16(const u16* g, u16* l) {
    __builtin_amdgcn_global_load_lds(
        (const __attribute__((address_space(1))) u32*)g,
        (__attribute__((address_space(3))) u32*)l, 16, 0, 0);
}

// ---------------------------------------------------------------------------
// Kernel 0: Wq|Wk|Wv -> per-K-chunk fragment-major image (proven):
//   chunk kc holds 24 frags of 1 KB: f = ksub*12 + nt; lane l of frag f gives
//   n = nt*16+(l&15), k = kc*64+ksub*32+(l>>4)*8+e.
// ---------------------------------------------------------------------------
__global__ void wt_kernel(const float* __restrict__ Wq, const float* __restrict__ Wk,
                          const float* __restrict__ Wv, u16* __restrict__ Wf) {
    int idx = blockIdx.x * 256 + threadIdx.x;          // 192*768
    int n = idx / Cc, k = idx % Cc;
    const float* W = (n < 64) ? Wq : (n < 128) ? Wk : Wv;
    float val = W[k * Hh + (n & 63)];
    int nt = n >> 4, fr = n & 15;
    int kc = k >> 6, ksub = (k >> 5) & 1, fk = k & 31;
    Wf[kc * 12288 + (ksub * 12 + nt) * 512 + (fr + ((fk >> 3) << 4)) * 8 + (fk & 7)] = f2bf(val);
}

// ---------------------------------------------------------------------------
// Kernel 1: QKV projection, SMALL blocks for 2 blocks/CU (the variable under
// test — every prior variant ran 1 block/CU, co-phasing all resident waves).
// Block = 64 rows of one batch, 256 thr = 4 waves; wave w owns m-tile w
// (16 rows x 192 cols, acc[12]).  12-chunk rotated dbuf loop (champion
// structure).  LDS = 65536 B exactly -> 2 blocks/CU:
//   XS dbuf [0,16384) 2x8KB | WS dbuf [16384,65536) 2x24KB
//   epilogue aliases [0,24576): qk [64][256B] 16KB | vt [64][128B] 8KB
// Epilogue: fragment-major q/k/v global write (r3-proven layout).
// ---------------------------------------------------------------------------
__global__ __launch_bounds__(256, 2) void proj_kernel(
        const float* __restrict__ x, const u16* __restrict__ Wf,
        u16* __restrict__ qf, u16* __restrict__ kf, u16* __restrict__ vf) {
    __shared__ u16 smem[32768];   // 65536 B
    char* smB = (char*)smem;

    const int tid = threadIdx.x;
    const int w = tid >> 6, l = tid & 63;
    const int lrow = l & 15, lgrp = l >> 4;
    const int b = blockIdx.x;                  // 2048 blocks: 64-row groups
    const int cswz = (lrow & 7) << 4;
    const size_t m0 = (size_t)b * 64;
    const int c0 = b % 12;

    const float* xg = x + (m0 + (tid >> 4)) * Cc + (tid & 15) * 4;

    float4 xr[4];
    f32x4 acc[12];
#pragma unroll
    for (int j = 0; j < 12; ++j) acc[j] = (f32x4)0.f;

#define XLOAD(kc_)                                                             \
    _Pragma("unroll")                                                          \
    for (int j = 0; j < 4; ++j)                                                \
        xr[j] = *(const float4*)(xg + (size_t)j * 16 * Cc + (kc_) * 64);

#define XWRITE(nb_)                                                            \
    {                                                                          \
        char* xb_ = smB + (nb_) * 8192;                                        \
        _Pragma("unroll")                                                      \
        for (int j = 0; j < 4; ++j) {                                          \
            int row = (tid >> 4) + j * 16;                                     \
            u16x4 pk;                                                          \
            pk[0] = f2bf(xr[j].x); pk[1] = f2bf(xr[j].y);                      \
            pk[2] = f2bf(xr[j].z); pk[3] = f2bf(xr[j].w);                      \
            *(u16x4*)(xb_ + ((row * 128 + (tid & 15) * 8) ^ ((row & 7) << 4))) = pk; \
        }                                                                      \
    }

#define WSTAGE(kc_, nb_)                                                       \
    {                                                                          \
        u16* wl_ = smem + 8192 + (nb_) * 12288;                                \
        const u16* wg_ = Wf + (size_t)(kc_) * 12288;                           \
        _Pragma("unroll")                                                      \
        for (int p = 0; p < 6; ++p)                                            \
            gll16(wg_ + p * 2048 + tid * 8, wl_ + p * 2048 + tid * 8);         \
    }

#define COMPUTE(cur_)                                                          \
    {                                                                          \
        const char* xb = smB + (cur_) * 8192;                                  \
        const char* wb = smB + 16384 + (cur_) * 24576;                         \
        _Pragma("unroll")                                                      \
        for (int ksub = 0; ksub < 2; ++ksub) {                                 \
            short8 bfr[12], af;                                                \
            _Pragma("unroll")                                                  \
            for (int nt = 0; nt < 12; ++nt)                                    \
                bfr[nt] = *(const short8*)(wb + (ksub * 12 + nt) * 1024 + l * 16); \
            af = *(const short8*)(xb +                                         \
                (((w * 16 + lrow) * 128 + ksub * 64 + lgrp * 16) ^ cswz));     \
            _Pragma("unroll")                                                  \
            for (int nt = 0; nt < 12; ++nt)                                    \
                acc[nt] = __builtin_amdgcn_mfma_f32_16x16x32_bf16(             \
                    af, bfr[nt], acc[nt], 0, 0, 0);                            \
        }                                                                      \
    }

    // ---- Phase 1 (rotated chunk order, champion loop) ----
    XLOAD(c0); WSTAGE(c0, 0); XWRITE(0);
    __syncthreads();
    int pn = c0;
    for (int kc = 0; kc < 12; ++kc) {
        const int cur = kc & 1;
        pn = (pn == 11) ? 0 : pn + 1;
        if (kc < 11) { WSTAGE(pn, cur ^ 1); XLOAD(pn); }
        COMPUTE(cur);
        if (kc < 11) { XWRITE(cur ^ 1); }
        __syncthreads();
    }
#undef XLOAD
#undef XWRITE
#undef WSTAGE
#undef COMPUTE

    // ---- Epilogue: scatter acc -> qk [64 s][256 B] + vt [64 h][128 B] ----
    char* qk = smB;
    char* vt = smB + 16384;
    const int sl = w * 16 + lgrp * 4;
#pragma unroll
    for (int nt = 0; nt < 12; ++nt) {
        f32x4 a = acc[nt];
        int n = nt * 16 + lrow;
        if (n < 128) {                          // q | k
#pragma unroll
            for (int r = 0; r < 4; ++r) {
                int row = sl + r;
                *(u16*)(qk + ((row * 256 + n * 2) ^ ((row & 7) << 4))) = f2bf(a[r]);
            }
        } else {                                // v (transposed)
            int h = n - 128;
            u16x4 pk;
            pk[0] = f2bf(a[0]); pk[1] = f2bf(a[1]);
            pk[2] = f2bf(a[2]); pk[3] = f2bf(a[3]);
            *(u16x4*)(vt + ((h * 128 + sl * 2) ^ ((h & 7) << 4))) = pk;
        }
    }
    __syncthreads();

    // ---- Gather 24 MFMA fragments, store fragment-major (coalesced 1 KB) ---
    const size_t rt0 = (size_t)b * 4;           // first 16-row tile index
    const int bidx = b >> 2;                    // batch
    const int ksb = (b & 3) * 2;                // s-chunk base
#pragma unroll
    for (int it = 0; it < 6; ++it) {
        int f = it * 4 + w;                     // 24 fragments
        const char* src;
        u16* dst;
        if (f < 8) {                            // Q frags
            int t = f >> 1, c = f & 1;
            int row = t * 16 + lrow;
            src = qk + ((row * 256 + (c * 32 + lgrp * 8) * 2) ^ ((row & 7) << 4));
            dst = qf + ((rt0 + t) * 2 + c) * 512 + l * 8;
        } else if (f < 16) {                    // K frags
            int g = f - 8, t = g >> 1, c = g & 1;
            int row = t * 16 + lrow;
            src = qk + ((row * 256 + 128 + (c * 32 + lgrp * 8) * 2) ^ ((row & 7) << 4));
            dst = kf + ((rt0 + t) * 2 + c) * 512 + l * 8;
        } else {                                // V frags
            int g = f - 16, ks = g >> 2, ht = g & 3;
            int row = ht * 16 + lrow;
            src = vt + ((row * 128 + (ks * 32 + lgrp * 8) * 2) ^ ((row & 7) << 4));
            dst = vf + (size_t)bidx * 16384 + ((ksb + ks) * 4 + ht) * 512 + l * 8;
        }
        short8 v = *(const short8*)src;
        *(short8*)dst = v;
    }
}

// ---------------------------------------------------------------------------
// Kernel 2: causal attention (r3-proven, verbatim); all fragment loads are
// coalesced 1 KB wave-loads from fragment-major qf/kf/vf (L2/L3-resident).
// ---------------------------------------------------------------------------
__global__ __launch_bounds__(256) void attn_kernel(
        const u16* __restrict__ qf, const u16* __restrict__ kf,
        const u16* __restrict__ vf, const int* __restrict__ pad,
        float* __restrict__ out) {
    __shared__ u16 Plds[4][16][264];

    const int wave = threadIdx.x >> 6, l = threadIdx.x & 63;
    const int lrow = l & 15, lgrp = l >> 4;
    const int b = blockIdx.x >> 2;
    const int i0 = (blockIdx.x & 3) * 64 + wave * 16;

    const u16* qb = qf + (size_t)(b * 16 + (i0 >> 4)) * 1024 + l * 8;
    short8 q0 = *(const short8*)qb;
    short8 q1 = *(const short8*)(qb + 512);

    f32x4 sreg[16];
    const u16* kb = kf + (size_t)b * 16384 + l * 8;
#pragma unroll
    for (int t = 0; t < 16; ++t) {
        short8 k0 = *(const short8*)(kb + t * 1024);
        short8 k1 = *(const short8*)(kb + t * 1024 + 512);
        f32x4 s = (f32x4)0.f;
        s = __builtin_amdgcn_mfma_f32_16x16x32_bf16(q0, k0, s, 0, 0, 0);
        s = __builtin_amdgcn_mfma_f32_16x16x32_bf16(q1, k1, s, 0, 0, 0);
#pragma unroll
        for (int r = 0; r < 4; ++r) {
            int i = i0 + lgrp * 4 + r;      // query row
            int sidx = t * 16 + lrow;       // key index
            sreg[t][r] = (sidx <= i) ? s[r] * 0.125f : -1e30f;
        }
    }

    f32x4 mx = sreg[0];
#pragma unroll
    for (int t = 1; t < 16; ++t)
#pragma unroll
        for (int r = 0; r < 4; ++r) mx[r] = fmaxf(mx[r], sreg[t][r]);
#pragma unroll
    for (int m = 1; m <= 8; m <<= 1)
#pragma unroll
        for (int r = 0; r < 4; ++r) mx[r] = fmaxf(mx[r], __shfl_xor(mx[r], m, 64));

    f32x4 sm = (f32x4)0.f;
#pragma unroll
    for (int t = 0; t < 16; ++t)
#pragma unroll
        for (int r = 0; r < 4; ++r) {
            float p = __expf(sreg[t][r] - mx[r]);
            sreg[t][r] = p;
            sm[r] += p;
        }
#pragma unroll
    for (int m = 1; m <= 8; m <<= 1)
#pragma unroll
        for (int r = 0; r < 4; ++r) sm[r] += __shfl_xor(sm[r], m, 64);

#pragma unroll
    for (int t = 0; t < 16; ++t)
#pragma unroll
        for (int r = 0; r < 4; ++r)
            Plds[wave][lgrp * 4 + r][t * 16 + lrow] = f2bf(sreg[t][r]);

    f32x4 o[4];
#pragma unroll
    for (int ht = 0; ht < 4; ++ht) o[ht] = (f32x4)0.f;
    const u16* vb0 = vf + (size_t)b * 16384 + l * 8;
#pragma unroll
    for (int ks = 0; ks < 8; ++ks) {
        short8 pa = *(const short8*)(&Plds[wave][lrow][ks * 32 + lgrp * 8]);
#pragma unroll
        for (int ht = 0; ht < 4; ++ht) {
            short8 vbf = *(const short8*)(vb0 + (ks * 4 + ht) * 512);
            o[ht] = __builtin_amdgcn_mfma_f32_16x16x32_bf16(pa, vbf, o[ht], 0, 0, 0);
        }
    }

#pragma unroll
    for (int r = 0; r < 4; ++r) {
        int i = i0 + lgrp * 4 + r;
        int pv = pad[b * Tt + i];
        float inv = (pv != 0) ? (1.0f / sm[r]) : 0.0f;
#pragma unroll
        for (int ht = 0; ht < 4; ++ht)
            out[((size_t)b * Tt + i) * Hh + ht * 16 + lrow] = o[ht][r] * inv;
    }
}

// ---------------------------------------------------------------------------
extern "C" void kernel_launch(void* const* d_in, const int* in_sizes, int n_in,
                              void* d_out, int out_size, void* d_ws, size_t ws_size,
                              hipStream_t stream) {
    const float* x  = (const float*)d_in[0];
    const float* Wq = (const float*)d_in[1];
    const float* Wk = (const float*)d_in[2];
    const float* Wv = (const float*)d_in[3];
    const int* pad  = (const int*)d_in[4];
    float* out = (float*)d_out;

    // Workspace (u16 units): Wf 147456 | qf 8388608 | kf 8388608 | vf 8388608
    u16* Wf = (u16*)d_ws;
    u16* qf = Wf + 147456;
    u16* kf = qf + 8388608;
    u16* vf = kf + 8388608;

    wt_kernel<<<576, 256, 0, stream>>>(Wq, Wk, Wv, Wf);
    proj_kernel<<<(Bb * Tt) / 64, 256, 0, stream>>>(x, Wf, qf, kf, vf);
    attn_kernel<<<Bb * 4, 256, 0, stream>>>(qf, kf, vf, pad, out);
}

// Round 18
// 119.628 us; speedup vs baseline: 1.5548x; 1.5548x over previous
//
#include <hip/hip_runtime.h>
#include <hip/hip_bf16.h>

typedef unsigned short u16;
typedef unsigned int u32;
typedef __attribute__((ext_vector_type(8))) short short8;   // 8 bf16 (4 VGPRs)
typedef __attribute__((ext_vector_type(4))) float f32x4;    // MFMA accumulator
typedef __attribute__((ext_vector_type(4))) u16 u16x4;

static constexpr int Bb = 512, Tt = 256, Cc = 768, Hh = 64;

__device__ __forceinline__ u16 f2bf(float f) {
    __hip_bfloat16 h = __float2bfloat16(f);   // RNE
    union { __hip_bfloat16 h; u16 u; } v; v.h = h;
    return v.u;
}

__device__ __forceinline__ void gll16(const u16* g, u16* l) {
    __builtin_amdgcn_global_load_lds(
        (const __attribute__((address_space(1))) u32*)g,
        (__attribute__((address_space(3))) u32*)l, 16, 0, 0);
}

// ---------------------------------------------------------------------------
// Kernel 0: Wq|Wk|Wv -> per-K-chunk fragment-major image (proven):
//   chunk kc holds 24 frags of 1 KB: f = ksub*12 + nt; lane l of frag f gives
//   n = nt*16+(l&15), k = kc*64+ksub*32+(l>>4)*8+e.
// ---------------------------------------------------------------------------
__global__ void wt_kernel(const float* __restrict__ Wq, const float* __restrict__ Wk,
                          const float* __restrict__ Wv, u16* __restrict__ Wf) {
    int idx = blockIdx.x * 256 + threadIdx.x;          // 192*768
    int n = idx / Cc, k = idx % Cc;
    const float* W = (n < 64) ? Wq : (n < 128) ? Wk : Wv;
    float val = W[k * Hh + (n & 63)];
    int nt = n >> 4, fr = n & 15;
    int kc = k >> 6, ksub = (k >> 5) & 1, fk = k & 31;
    Wf[kc * 12288 + (ksub * 12 + nt) * 512 + (fr + ((fk >> 3) << 4)) * 8 + (fk & 7)] = f2bf(val);
}

// ---------------------------------------------------------------------------
// Fused kernel: one block per batch. 512 thr = 8 waves.  The r13 champion
// (119.7 us): per-block K-chunk rotation c0=b%12 decorrelates the HBM access
// phase across blocks; XS dbuf + WS dbuf phase-1 (compiler-scheduled, plain
// __syncthreads); LDS-bounce epilogue; per-wave causal attention phase-2.
// Ten structural variants (counted-vmcnt x2, reg-staged, no-drain 3-buf,
// K=128, direct-reg A-frags, raw-f32 staging, 2-blk/CU, persistence) all
// converge at ~3.8 TB/s effective read throughput -> this structure sits on
// the empirical pure-read ceiling for this access shape.
// LDS map (bytes): phase1: XS dbuf [0,65536) | WS dbuf [65536,114688)
//                  phase2: KT [0,32768) | VT [32768,65536) | QB [65536,98304)
//                          P [98304,118784)
// ---------------------------------------------------------------------------
__global__ __launch_bounds__(512, 2) void fused_kernel(
        const float* __restrict__ x, const u16* __restrict__ Wf,
        const int* __restrict__ pad, float* __restrict__ out) {
    __shared__ u16 smem[59392];   // 118784 B
    char* smB = (char*)smem;

    const int tid = threadIdx.x;
    const int w = tid >> 6, l = tid & 63;
    const int lrow = l & 15, lgrp = l >> 4;
    const int b = blockIdx.x;
    const int cswz = (lrow & 7) << 4;
    const int tt0 = w, tt1 = 15 - w;          // owned query-row tiles
    const int c0 = b % 12;                     // per-block chunk rotation phase

    const float* xg = x + ((size_t)b * Tt + (tid >> 4)) * Cc + (tid & 15) * 4;

    float4 xr[8];
    f32x4 acc[2][12];
#pragma unroll
    for (int i = 0; i < 2; ++i)
#pragma unroll
        for (int j = 0; j < 12; ++j) acc[i][j] = (f32x4)0.f;

#define XLOAD(kc_)                                                             \
    _Pragma("unroll")                                                          \
    for (int j = 0; j < 8; ++j)                                                \
        xr[j] = *(const float4*)(xg + (size_t)j * 32 * Cc + (kc_) * 64);

#define XWRITE(nb_)                                                            \
    {                                                                          \
        char* xb_ = smB + (nb_) * 32768;                                       \
        _Pragma("unroll")                                                      \
        for (int j = 0; j < 8; ++j) {                                          \
            int row = j * 32 + (tid >> 4);                                     \
            u16x4 pk;                                                          \
            pk[0] = f2bf(xr[j].x); pk[1] = f2bf(xr[j].y);                      \
            pk[2] = f2bf(xr[j].z); pk[3] = f2bf(xr[j].w);                      \
            *(u16x4*)(xb_ + ((row * 128 + (tid & 15) * 8) ^ ((row & 7) << 4))) = pk; \
        }                                                                      \
    }

#define WSTAGE(kc_, nb_)                                                       \
    {                                                                          \
        u16* wl_ = smem + 32768 + (nb_) * 12288;                               \
        const u16* wg_ = Wf + (size_t)(kc_) * 12288;                           \
        _Pragma("unroll")                                                      \
        for (int p = 0; p < 3; ++p)                                            \
            gll16(wg_ + (p * 8 + w) * 512 + l * 8, wl_ + (p * 8 + w) * 512);   \
    }

#define COMPUTE(cur_)                                                          \
    {                                                                          \
        const char* xb = smB + (cur_) * 32768;                                 \
        const char* wb = smB + 65536 + (cur_) * 24576;                         \
        _Pragma("unroll")                                                      \
        for (int ksub = 0; ksub < 2; ++ksub) {                                 \
            short8 bfr[12], af[2];                                             \
            _Pragma("unroll")                                                  \
            for (int nt = 0; nt < 12; ++nt)                                    \
                bfr[nt] = *(const short8*)(wb + (ksub * 12 + nt) * 1024 + l * 16); \
            af[0] = *(const short8*)(xb +                                      \
                (((tt0 * 16 + lrow) * 128 + ksub * 64 + lgrp * 16) ^ cswz));   \
            af[1] = *(const short8*)(xb +                                      \
                (((tt1 * 16 + lrow) * 128 + ksub * 64 + lgrp * 16) ^ cswz));   \
            _Pragma("unroll")                                                  \
            for (int mrep = 0; mrep < 2; ++mrep)                               \
                _Pragma("unroll")                                              \
                for (int nt = 0; nt < 12; ++nt)                                \
                    acc[mrep][nt] = __builtin_amdgcn_mfma_f32_16x16x32_bf16(   \
                        af[mrep], bfr[nt], acc[mrep][nt], 0, 0, 0);            \
        }                                                                      \
    }

    // ---- Phase 1 (rotated chunk order) ----
    XLOAD(c0); WSTAGE(c0, 0); XWRITE(0);
    __syncthreads();
    int pn = c0;                               // pn tracks (c0+kc+1)%12
    for (int kc = 0; kc < 12; ++kc) {
        const int cur = kc & 1;
        pn = (pn == 11) ? 0 : pn + 1;
        if (kc < 11) { WSTAGE(pn, cur ^ 1); XLOAD(pn); }
        COMPUTE(cur);
        if (kc < 11) { XWRITE(cur ^ 1); }
        __syncthreads();
    }
#undef XLOAD
#undef XWRITE
#undef WSTAGE
#undef COMPUTE

    // ---- Epilogue: acc -> KT / VT / QB ----
#pragma unroll
    for (int mrep = 0; mrep < 2; ++mrep) {
        const int tt = (mrep == 0) ? tt0 : tt1;
        const int s0 = tt * 16;
#pragma unroll
        for (int nt = 0; nt < 12; ++nt) {
            f32x4 a = acc[mrep][nt];
            if (nt < 4) {                       // Q -> QB [256][64]
                int h = nt * 16 + lrow;
#pragma unroll
                for (int r = 0; r < 4; ++r) {
                    int row = s0 + lgrp * 4 + r;
                    *(u16*)(smB + 65536 + ((row * 128 + h * 2) ^ ((row & 7) << 4))) = f2bf(a[r]);
                }
            } else if (nt < 8) {                // K -> KT [256][64]
                int h = (nt - 4) * 16 + lrow;
#pragma unroll
                for (int r = 0; r < 4; ++r) {
                    int s = s0 + lgrp * 4 + r;
                    *(u16*)(smB + ((s * 128 + h * 2) ^ ((s & 7) << 4))) = f2bf(a[r]);
                }
            } else {                            // V -> VT [64][256]
                int h = (nt - 8) * 16 + lrow;
                int s = s0 + lgrp * 4;
                u16x4 pk;
                pk[0] = f2bf(a[0]); pk[1] = f2bf(a[1]);
                pk[2] = f2bf(a[2]); pk[3] = f2bf(a[3]);
                *(u16x4*)(smB + 32768 + h * 512 + ((s * 2) ^ ((h & 15) << 4))) = pk;
            }
        }
    }
    __syncthreads();

    // Q fragment readback
    short8 qfr[2][2];
#pragma unroll
    for (int mt = 0; mt < 2; ++mt) {
        const int tt = (mt == 0) ? tt0 : tt1;
#pragma unroll
        for (int kk = 0; kk < 2; ++kk)
            qfr[mt][kk] = *(const short8*)(smB + 65536 +
                (((tt * 16 + lrow) * 128 + kk * 64 + lgrp * 16) ^ cswz));
    }
    __syncthreads();    // all qfr reads done before P overwrites QB space

    // ---- Phase 2: causal attention (per-wave, no barriers) ----
    char* pbase = smB + 98304 + w * 2560;
#pragma unroll
    for (int mt = 0; mt < 2; ++mt) {
        const int tt = (mt == 0) ? tt0 : tt1;
        const int i0 = tt * 16;

        f32x4 sreg[16];
#pragma unroll
        for (int t = 0; t < 16; ++t) {
            if (t <= tt) {
                short8 k0 = *(const short8*)(smB +
                    (((t * 16 + lrow) * 128 + lgrp * 16) ^ cswz));
                short8 k1 = *(const short8*)(smB +
                    (((t * 16 + lrow) * 128 + 64 + lgrp * 16) ^ cswz));
                f32x4 s = (f32x4)0.f;
                s = __builtin_amdgcn_mfma_f32_16x16x32_bf16(qfr[mt][0], k0, s, 0, 0, 0);
                s = __builtin_amdgcn_mfma_f32_16x16x32_bf16(qfr[mt][1], k1, s, 0, 0, 0);
                if (t == tt) {
#pragma unroll
                    for (int r = 0; r < 4; ++r) {
                        int i = i0 + lgrp * 4 + r;
                        int sidx = t * 16 + lrow;
                        sreg[t][r] = (sidx <= i) ? s[r] * 0.125f : -1e30f;
                    }
                } else {
#pragma unroll
                    for (int r = 0; r < 4; ++r) sreg[t][r] = s[r] * 0.125f;
                }
            }
        }

        f32x4 mx = (f32x4)(-1e30f);
#pragma unroll
        for (int t = 0; t < 16; ++t)
            if (t <= tt)
#pragma unroll
                for (int r = 0; r < 4; ++r) mx[r] = fmaxf(mx[r], sreg[t][r]);
#pragma unroll
        for (int m = 1; m <= 8; m <<= 1)
#pragma unroll
            for (int r = 0; r < 4; ++r) mx[r] = fmaxf(mx[r], __shfl_xor(mx[r], m, 64));

        f32x4 sm = (f32x4)0.f;
#pragma unroll
        for (int t = 0; t < 16; ++t)
            if (t <= tt)
#pragma unroll
                for (int r = 0; r < 4; ++r) {
                    float p = __expf(sreg[t][r] - mx[r]);
                    sreg[t][r] = p;
                    sm[r] += p;
                }
#pragma unroll
        for (int m = 1; m <= 8; m <<= 1)
#pragma unroll
            for (int r = 0; r < 4; ++r) sm[r] += __shfl_xor(sm[r], m, 64);

        float inv[4];
#pragma unroll
        for (int r = 0; r < 4; ++r) {
            int i = i0 + lgrp * 4 + r;
            inv[r] = (pad[b * Tt + i] != 0) ? (1.0f / sm[r]) : 0.0f;
        }

        f32x4 o[4];
#pragma unroll
        for (int ht = 0; ht < 4; ++ht) o[ht] = (f32x4)0.f;
#pragma unroll
        for (int ks = 0; ks < 8; ++ks) {
            if (2 * ks <= tt) {
                char* pb = pbase + (ks & 1) * 1280;
#pragma unroll
                for (int r = 0; r < 4; ++r) {
                    int prow = lgrp * 4 + r;
                    *(u16*)(pb + prow * 80 + lrow * 2) = f2bf(sreg[2 * ks][r]);
                    u16 pv2 = (2 * ks + 1 <= tt) ? f2bf(sreg[2 * ks + 1][r]) : (u16)0;
                    *(u16*)(pb + prow * 80 + 32 + lrow * 2) = pv2;
                }
                short8 pa = *(const short8*)(pb + lrow * 80 + lgrp * 16);
#pragma unroll
                for (int ht = 0; ht < 4; ++ht) {
                    short8 vfr = *(const short8*)(smB + 32768 + (ht * 16 + lrow) * 512 +
                        ((ks * 64 + lgrp * 16) ^ (lrow << 4)));
                    o[ht] = __builtin_amdgcn_mfma_f32_16x16x32_bf16(pa, vfr, o[ht], 0, 0, 0);
                }
            }
        }

        float* outp = out + ((size_t)b * Tt + i0) * Hh;
#pragma unroll
        for (int r = 0; r < 4; ++r)
#pragma unroll
            for (int ht = 0; ht < 4; ++ht)
                outp[(lgrp * 4 + r) * Hh + ht * 16 + lrow] = o[ht][r] * inv[r];
    }
}

// ---------------------------------------------------------------------------
extern "C" void kernel_launch(void* const* d_in, const int* in_sizes, int n_in,
                              void* d_out, int out_size, void* d_ws, size_t ws_size,
                              hipStream_t stream) {
    const float* x  = (const float*)d_in[0];
    const float* Wq = (const float*)d_in[1];
    const float* Wk = (const float*)d_in[2];
    const float* Wv = (const float*)d_in[3];
    const int* pad  = (const int*)d_in[4];
    float* out = (float*)d_out;

    u16* Wf = (u16*)d_ws;    // 294912 B

    wt_kernel<<<576, 256, 0, stream>>>(Wq, Wk, Wv, Wf);
    fused_kernel<<<Bb, 512, 0, stream>>>(x, Wf, pad, out);
}